// Round 2
// baseline (3046.216 us; speedup 1.0000x reference)
//
#include <hip/hip_runtime.h>
#include <hip/hip_bf16.h>
#include <math.h>

#define N_NODES 100000
#define N_EDGES 6400000
#define D_IN 512
#define D_HID 16
#define NB 391          // ceil(100000/256) coarse buckets by dst>>8

// ---------------- coarse histogram of dst>>8 (LDS-staged) ----------------
__global__ __launch_bounds__(256) void khist(const int* __restrict__ dst,
                                             int* __restrict__ bhist) {
    __shared__ int h[NB];
    int tid = threadIdx.x;
    for (int i = tid; i < NB; i += 256) h[i] = 0;
    __syncthreads();
    int base = blockIdx.x * 25600;
#pragma unroll 4
    for (int k = 0; k < 100; k++) {
        int e = base + k * 256 + tid;
        atomicAdd(&h[dst[e] >> 8], 1);
    }
    __syncthreads();
    for (int i = tid; i < NB; i += 256) atomicAdd(&bhist[i], h[i]);
}

// ---------------- scan buckets -> base, init cursor ----------------
__global__ void bscan(const int* __restrict__ bhist, int* __restrict__ bbase,
                      int* __restrict__ bcur) {
    __shared__ int sd[512];
    int tid = threadIdx.x;
    int v = (tid < NB) ? bhist[tid] : 0;
    sd[tid] = v;
    __syncthreads();
    for (int off = 1; off < 512; off <<= 1) {
        int u = (tid >= off) ? sd[tid - off] : 0;
        __syncthreads();
        sd[tid] += u;
        __syncthreads();
    }
    if (tid < NB) {
        int excl = sd[tid] - v;
        bbase[tid] = excl;
        bcur[tid] = excl;
    }
}

// ---------------- coarse scatter: pack (src<<8)|(dst&255) ----------------
// 391 hot cursors -> each 64B line of ebuf fills within ~50ns -> L2 absorbs,
// full-line evictions only (vs 15x write amp with 100k cursors).
__global__ __launch_bounds__(256) void kscatter(const int* __restrict__ src,
                                                const int* __restrict__ dst,
                                                int* __restrict__ bcur,
                                                unsigned int* __restrict__ ebuf) {
    int e = blockIdx.x * 256 + threadIdx.x;
    int d = dst[e];
    int s = src[e];
    int b = d >> 8;
    int pos = atomicAdd(&bcur[b], 1);
    ebuf[pos] = ((unsigned int)s << 8) | (unsigned int)(d & 255);
}

// ---------------- per-bucket degree histogram (no global atomics) ----------------
__global__ __launch_bounds__(1024) void kdeg(const unsigned int* __restrict__ ebuf,
                                             const int* __restrict__ bhist,
                                             const int* __restrict__ bbase,
                                             int* __restrict__ deg) {
    __shared__ int h[256];
    int tid = threadIdx.x;
    int b = blockIdx.x;
    if (tid < 256) h[tid] = 0;
    __syncthreads();
    int cnt = bhist[b];
    int start = bbase[b];
    for (int i = tid; i < cnt; i += 1024) {
        unsigned int v = ebuf[start + i];
        atomicAdd(&h[v & 255u], 1);
    }
    __syncthreads();
    if (tid < 256) {
        int node = b * 256 + tid;
        if (node < N_NODES) deg[node] = h[tid];
    }
}

__global__ void dinv_kernel(const int* __restrict__ deg, float* __restrict__ dinv) {
    int i = blockIdx.x * blockDim.x + threadIdx.x;
    if (i < N_NODES) dinv[i] = rsqrtf((float)deg[i] + 1.0f);  // +1 self-loop
}

// ---------------- prefix sum over deg (chunk=1024/block) ----------------
__global__ void scan1(const int* __restrict__ deg, int* __restrict__ row_start,
                      int* __restrict__ bsum) {
    __shared__ int sd[256];
    int tid = threadIdx.x;
    int base = blockIdx.x * 1024 + tid * 4;
    int d0 = 0, d1 = 0, d2 = 0, d3 = 0;
    if (base + 3 < N_NODES) {
        d0 = deg[base]; d1 = deg[base + 1]; d2 = deg[base + 2]; d3 = deg[base + 3];
    } else {
        if (base < N_NODES) d0 = deg[base];
        if (base + 1 < N_NODES) d1 = deg[base + 1];
        if (base + 2 < N_NODES) d2 = deg[base + 2];
    }
    int s = d0 + d1 + d2 + d3;
    sd[tid] = s;
    __syncthreads();
    for (int off = 1; off < 256; off <<= 1) {
        int v = (tid >= off) ? sd[tid - off] : 0;
        __syncthreads();
        sd[tid] += v;
        __syncthreads();
    }
    int excl = sd[tid] - s;
    if (base < N_NODES) row_start[base] = excl;
    if (base + 1 < N_NODES) row_start[base + 1] = excl + d0;
    if (base + 2 < N_NODES) row_start[base + 2] = excl + d0 + d1;
    if (base + 3 < N_NODES) row_start[base + 3] = excl + d0 + d1 + d2;
    if (tid == 255) bsum[blockIdx.x] = sd[255];
}

__global__ void scan2(int* __restrict__ bsum, int nb) {
    __shared__ int sd[128];
    int tid = threadIdx.x;
    int v = (tid < nb) ? bsum[tid] : 0;
    sd[tid] = v;
    __syncthreads();
    for (int off = 1; off < 128; off <<= 1) {
        int u = (tid >= off) ? sd[tid - off] : 0;
        __syncthreads();
        sd[tid] += u;
        __syncthreads();
    }
    if (tid < nb) bsum[tid] = sd[tid] - v;  // exclusive
}

__global__ void scan3(int* __restrict__ row_start, const int* __restrict__ bsum) {
    int off = bsum[blockIdx.x];
    int base = blockIdx.x * 1024 + threadIdx.x * 4;
#pragma unroll
    for (int j = 0; j < 4; j++) {
        int i = base + j;
        if (i < N_NODES) row_start[i] += off;
    }
}

// ---------------- per-bucket placement with LDS cursors ----------------
// csr writes confined to one contiguous ~64KB region per block -> L2 absorbs.
__global__ __launch_bounds__(1024) void kplace(const unsigned int* __restrict__ ebuf,
                                               const int* __restrict__ bhist,
                                               const int* __restrict__ bbase,
                                               const int* __restrict__ row_start,
                                               int* __restrict__ csr) {
    __shared__ int cur[256];
    int tid = threadIdx.x;
    int b = blockIdx.x;
    if (tid < 256) {
        int node = b * 256 + tid;
        cur[tid] = (node < N_NODES) ? row_start[node] : 0;
    }
    __syncthreads();
    int cnt = bhist[b];
    int start = bbase[b];
    for (int i = tid; i < cnt; i += 1024) {
        unsigned int v = ebuf[start + i];
        int p = atomicAdd(&cur[v & 255u], 1);
        csr[p] = (int)(v >> 8);
    }
}

// ---------------- GEMM1: h1 = x @ W1  [100000x512]@[512x16] ----------------
__global__ __launch_bounds__(256) void gemm1(const float* __restrict__ x,
                                             const float* __restrict__ W1,
                                             float* __restrict__ h1) {
    __shared__ float xs[256 * 33];
    int tid = threadIdx.x;
    int row0 = blockIdx.x * 256;
    int row = row0 + tid;
    float acc[16];
#pragma unroll
    for (int c = 0; c < 16; c++) acc[c] = 0.f;

    for (int k0 = 0; k0 < D_IN; k0 += 32) {
        __syncthreads();
#pragma unroll
        for (int l = 0; l < 8; l++) {
            int idx = tid + l * 256;
            int r = idx >> 3;
            int f4 = idx & 7;
            int gr = row0 + r;
            float4 v = make_float4(0.f, 0.f, 0.f, 0.f);
            if (gr < N_NODES)
                v = *(const float4*)(x + (size_t)gr * D_IN + k0 + f4 * 4);
            int a = r * 33 + f4 * 4;
            xs[a] = v.x; xs[a + 1] = v.y; xs[a + 2] = v.z; xs[a + 3] = v.w;
        }
        __syncthreads();
#pragma unroll
        for (int kk = 0; kk < 32; kk++) {
            float xv = xs[tid * 33 + kk];
            const float* wr = W1 + (k0 + kk) * 16;
#pragma unroll
            for (int c = 0; c < 16; c++) acc[c] = fmaf(xv, wr[c], acc[c]);
        }
    }
    if (row < N_NODES) {
        float4* o = (float4*)(h1 + (size_t)row * 16);
        o[0] = make_float4(acc[0], acc[1], acc[2], acc[3]);
        o[1] = make_float4(acc[4], acc[5], acc[6], acc[7]);
        o[2] = make_float4(acc[8], acc[9], acc[10], acc[11]);
        o[3] = make_float4(acc[12], acc[13], acc[14], acc[15]);
    }
}

// ---------------- Agg layer 1 (pull) + bias + ReLU + @W2 fused ----------------
__global__ __launch_bounds__(256) void agg1(const float* __restrict__ h1,
                                            const float* __restrict__ dinv,
                                            const int* __restrict__ row_start,
                                            const int* __restrict__ deg,
                                            const int* __restrict__ csr,
                                            const float* __restrict__ b1,
                                            const float* __restrict__ W2,
                                            float* __restrict__ h3) {
    int tid = threadIdx.x;
    int node = blockIdx.x * 16 + (tid >> 4);
    int c = tid & 15;
    if (node >= N_NODES) return;
    float di = dinv[node];
    float acc = h1[(size_t)node * 16 + c] * di * di;  // self-loop
    int start = row_start[node];
    int cnt = deg[node];
    int sN = 0; float vN = 0.f, dN = 0.f;
    if (cnt > 0) {
        sN = csr[start];
        vN = h1[(size_t)sN * 16 + c];
        dN = dinv[sN];
    }
    for (int t = 0; t < cnt; t++) {
        float vC = vN, dC = dN;
        if (t + 1 < cnt) {
            int s = csr[start + t + 1];
            vN = h1[(size_t)s * 16 + c];
            dN = dinv[s];
        }
        acc = fmaf(vC, dC * di, acc);
    }
    float v = acc + b1[c];
    v = v > 0.f ? v : 0.f;
    float out = 0.f;
#pragma unroll
    for (int j = 0; j < 16; j++) {
        float vj = __shfl(v, j, 16);
        out = fmaf(vj, W2[j * 16 + c], out);
    }
    h3[(size_t)node * 16 + c] = out;
}

// ---------------- Agg layer 2 (pull) + bias + log_softmax ----------------
__global__ __launch_bounds__(256) void agg2(const float* __restrict__ h3,
                                            const float* __restrict__ dinv,
                                            const int* __restrict__ row_start,
                                            const int* __restrict__ deg,
                                            const int* __restrict__ csr,
                                            const float* __restrict__ b2,
                                            float* __restrict__ out) {
    int tid = threadIdx.x;
    int node = blockIdx.x * 16 + (tid >> 4);
    int c = tid & 15;
    if (node >= N_NODES) return;
    float di = dinv[node];
    float acc = h3[(size_t)node * 16 + c] * di * di;
    int start = row_start[node];
    int cnt = deg[node];
    int sN = 0; float vN = 0.f, dN = 0.f;
    if (cnt > 0) {
        sN = csr[start];
        vN = h3[(size_t)sN * 16 + c];
        dN = dinv[sN];
    }
    for (int t = 0; t < cnt; t++) {
        float vC = vN, dC = dN;
        if (t + 1 < cnt) {
            int s = csr[start + t + 1];
            vN = h3[(size_t)s * 16 + c];
            dN = dinv[s];
        }
        acc = fmaf(vC, dC * di, acc);
    }
    float logit = acc + b2[c];
    float m = logit;
#pragma unroll
    for (int mask = 1; mask < 16; mask <<= 1)
        m = fmaxf(m, __shfl_xor(m, mask, 16));
    float e = expf(logit - m);
    float ssum = e;
#pragma unroll
    for (int mask = 1; mask < 16; mask <<= 1)
        ssum += __shfl_xor(ssum, mask, 16);
    out[(size_t)node * 16 + c] = (logit - m) - logf(ssum);
}

extern "C" void kernel_launch(void* const* d_in, const int* in_sizes, int n_in,
                              void* d_out, int out_size, void* d_ws, size_t ws_size,
                              hipStream_t stream) {
    const float* x  = (const float*)d_in[0];
    const float* W1 = (const float*)d_in[1];
    const float* b1 = (const float*)d_in[2];
    const float* W2 = (const float*)d_in[3];
    const float* b2 = (const float*)d_in[4];
    const int*   ei = (const int*)d_in[5];
    const int* src = ei;
    const int* dst = ei + N_EDGES;
    float* out = (float*)d_out;

    // workspace layout (4B elements):
    int* deg       = (int*)d_ws;                 // 100352
    int* row_start = deg + 100352;               // 100352
    float* dinv    = (float*)(row_start + 100352); // 100352
    int* bsum      = (int*)(dinv + 100352);      // 128
    int* bhist     = bsum + 128;                 // 512
    int* bbase     = bhist + 512;                // 512
    int* bcur      = bbase + 512;                // 512
    unsigned int* ebuf = (unsigned int*)(bcur + 512);  // 6.4M
    int* csr       = (int*)(ebuf + N_EDGES);     // 6.4M
    float* h1      = (float*)(csr + N_EDGES);    // 1.6M
    float* h3      = h1 + 1600000;               // 1.6M

    hipMemsetAsync(bhist, 0, NB * sizeof(int), stream);
    khist<<<250, 256, 0, stream>>>(dst, bhist);
    bscan<<<1, 512, 0, stream>>>(bhist, bbase, bcur);
    kscatter<<<N_EDGES / 256, 256, 0, stream>>>(src, dst, bcur, ebuf);
    kdeg<<<NB, 1024, 0, stream>>>(ebuf, bhist, bbase, deg);
    dinv_kernel<<<(N_NODES + 255) / 256, 256, 0, stream>>>(deg, dinv);
    scan1<<<98, 256, 0, stream>>>(deg, row_start, bsum);
    scan2<<<1, 128, 0, stream>>>(bsum, 98);
    scan3<<<98, 256, 0, stream>>>(row_start, bsum);
    kplace<<<NB, 1024, 0, stream>>>(ebuf, bhist, bbase, row_start, csr);
    gemm1<<<(N_NODES + 255) / 256, 256, 0, stream>>>(x, W1, h1);
    agg1<<<(N_NODES + 15) / 16, 256, 0, stream>>>(h1, dinv, row_start, deg, csr, b1, W2, h3);
    agg2<<<(N_NODES + 15) / 16, 256, 0, stream>>>(h3, dinv, row_start, deg, csr, b2, out);
}

// Round 3
// 1898.446 us; speedup vs baseline: 1.6046x; 1.6046x over previous
//
#include <hip/hip_runtime.h>
#include <hip/hip_bf16.h>
#include <math.h>

#define N_NODES 100000
#define N_EDGES 6400000
#define D_IN 512
#define D_HID 16

#define NBKT 782        // ceil(100000/128) buckets of 128 nodes (by dst>>7)
#define NBP  784        // padded row stride for (block x bucket) matrices
#define NBLK 1000       // scatter blocks
#define EPB  6400       // edges per scatter block (25 per thread * 256)

// ---------------- pass A: per-block bucket histogram (no global atomics) ----
__global__ __launch_bounds__(256) void khist(const int* __restrict__ dst,
                                             int* __restrict__ hist_mat) {
    __shared__ int h[NBP];
    int tid = threadIdx.x;
    int blk = blockIdx.x;
    for (int i = tid; i < NBP; i += 256) h[i] = 0;
    __syncthreads();
    int base = blk * EPB;
#pragma unroll
    for (int k = 0; k < 25; k++)
        atomicAdd(&h[dst[base + k * 256 + tid] >> 7], 1);
    __syncthreads();
    for (int i = tid; i < NBKT; i += 256) hist_mat[blk * NBP + i] = h[i];
}

// ---------------- bucket totals ----------------
__global__ __launch_bounds__(256) void kbtot(const int* __restrict__ hist_mat,
                                             int* __restrict__ btot) {
    __shared__ int sd[256];
    int b = blockIdx.x;
    int t = threadIdx.x;
    int s = 0;
    for (int r = t; r < NBLK; r += 256) s += hist_mat[r * NBP + b];
    sd[t] = s;
    __syncthreads();
    for (int off = 128; off > 0; off >>= 1) {
        if (t < off) sd[t] += sd[t + off];
        __syncthreads();
    }
    if (t == 0) btot[b] = sd[0];
}

// ---------------- exclusive scan of bucket totals ----------------
__global__ __launch_bounds__(1024) void kbscan(const int* __restrict__ btot,
                                               int* __restrict__ bbase) {
    __shared__ int sd[1024];
    int t = threadIdx.x;
    int v = (t < NBKT) ? btot[t] : 0;
    sd[t] = v;
    __syncthreads();
    for (int off = 1; off < 1024; off <<= 1) {
        int u = (t >= off) ? sd[t - off] : 0;
        __syncthreads();
        sd[t] += u;
        __syncthreads();
    }
    if (t < NBKT) bbase[t] = sd[t] - v;
}

// ---------------- per-bucket exclusive scan over blocks ----------------
__global__ __launch_bounds__(256) void kbase(const int* __restrict__ hist_mat,
                                             const int* __restrict__ bbase,
                                             int* __restrict__ base_mat) {
    __shared__ int sd[256];
    __shared__ int chunk_tot;
    int b = blockIdx.x;
    int t = threadIdx.x;
    int running = bbase[b];
    for (int c0 = 0; c0 < NBLK; c0 += 256) {
        int r = c0 + t;
        int v = (r < NBLK) ? hist_mat[r * NBP + b] : 0;
        sd[t] = v;
        __syncthreads();
        for (int off = 1; off < 256; off <<= 1) {
            int u = (t >= off) ? sd[t - off] : 0;
            __syncthreads();
            sd[t] += u;
            __syncthreads();
        }
        if (r < NBLK) base_mat[r * NBP + b] = running + sd[t] - v;
        if (t == 255) chunk_tot = sd[255];
        __syncthreads();
        running += chunk_tot;
        __syncthreads();
    }
}

// ---------------- pass C: deterministic scatter via LDS cursors ----------
// Each (block,bucket) region is written by exactly one block -> one XCD ->
// lines fill in one L2, full-line evictions only.
__global__ __launch_bounds__(256) void kscatter(const int* __restrict__ src,
                                                const int* __restrict__ dst,
                                                const int* __restrict__ base_mat,
                                                unsigned int* __restrict__ ebuf) {
    __shared__ int cur[NBP];
    int tid = threadIdx.x;
    int blk = blockIdx.x;
    for (int i = tid; i < NBKT; i += 256) cur[i] = base_mat[blk * NBP + i];
    __syncthreads();
    int base = blk * EPB;
#pragma unroll 4
    for (int k = 0; k < 25; k++) {
        int e = base + k * 256 + tid;
        int d = dst[e];
        int s = src[e];
        int p = atomicAdd(&cur[d >> 7], 1);
        ebuf[p] = ((unsigned int)s << 7) | (unsigned int)(d & 127);
    }
}

// ---------------- per-bucket degree -> dinv (no global atomics) ----------
__global__ __launch_bounds__(256) void kdeg(const unsigned int* __restrict__ ebuf,
                                            const int* __restrict__ btot,
                                            const int* __restrict__ bbase,
                                            float* __restrict__ dinv) {
    __shared__ int h[128];
    int t = threadIdx.x;
    int b = blockIdx.x;
    if (t < 128) h[t] = 0;
    __syncthreads();
    int cnt = btot[b];
    int start = bbase[b];
    for (int i = t; i < cnt; i += 256)
        atomicAdd(&h[ebuf[start + i] & 127u], 1);
    __syncthreads();
    if (t < 128) {
        int node = b * 128 + t;
        if (node < N_NODES) dinv[node] = rsqrtf((float)h[t] + 1.0f);
    }
}

// ---------------- GEMM1: h1p = (x @ W1) * dinv[row]  ----------------
__global__ __launch_bounds__(256) void gemm1(const float* __restrict__ x,
                                             const float* __restrict__ W1,
                                             const float* __restrict__ dinv,
                                             float* __restrict__ h1p) {
    __shared__ float xs[256 * 33];
    int tid = threadIdx.x;
    int row0 = blockIdx.x * 256;
    int row = row0 + tid;
    float acc[16];
#pragma unroll
    for (int c = 0; c < 16; c++) acc[c] = 0.f;

    for (int k0 = 0; k0 < D_IN; k0 += 32) {
        __syncthreads();
#pragma unroll
        for (int l = 0; l < 8; l++) {
            int idx = tid + l * 256;
            int r = idx >> 3;
            int f4 = idx & 7;
            int gr = row0 + r;
            float4 v = make_float4(0.f, 0.f, 0.f, 0.f);
            if (gr < N_NODES)
                v = *(const float4*)(x + (size_t)gr * D_IN + k0 + f4 * 4);
            int a = r * 33 + f4 * 4;
            xs[a] = v.x; xs[a + 1] = v.y; xs[a + 2] = v.z; xs[a + 3] = v.w;
        }
        __syncthreads();
#pragma unroll
        for (int kk = 0; kk < 32; kk++) {
            float xv = xs[tid * 33 + kk];
            const float* wr = W1 + (k0 + kk) * 16;
#pragma unroll
            for (int c = 0; c < 16; c++) acc[c] = fmaf(xv, wr[c], acc[c]);
        }
    }
    if (row < N_NODES) {
        float di = dinv[row];
        float4* o = (float4*)(h1p + (size_t)row * 16);
        o[0] = make_float4(acc[0] * di, acc[1] * di, acc[2] * di, acc[3] * di);
        o[1] = make_float4(acc[4] * di, acc[5] * di, acc[6] * di, acc[7] * di);
        o[2] = make_float4(acc[8] * di, acc[9] * di, acc[10] * di, acc[11] * di);
        o[3] = make_float4(acc[12] * di, acc[13] * di, acc[14] * di, acc[15] * di);
    }
}

// ---------------- Agg layer 1: LDS accumulate + bias + ReLU + @W2, scaled ---
// out stored pre-scaled: h3p[n] = (relu(dinv[n]*(sum+self)+b1) @ W2) * dinv[n]
__global__ __launch_bounds__(512) void kagg1(const float* __restrict__ h1p,
                                             const float* __restrict__ dinv,
                                             const unsigned int* __restrict__ ebuf,
                                             const int* __restrict__ btot,
                                             const int* __restrict__ bbase,
                                             const float* __restrict__ b1,
                                             const float* __restrict__ W2,
                                             float* __restrict__ h3p) {
    __shared__ float acc[128 * 16];
    __shared__ float dinvb[128];
    __shared__ float w2s[256];
    __shared__ float b1s[16];
    int t = threadIdx.x;
    int b = blockIdx.x;
    int nb0 = b * 128;
    if (t < 128) {
        int n = nb0 + t;
        dinvb[t] = (n < N_NODES) ? dinv[n] : 0.f;
    }
    if (t >= 128 && t < 384) w2s[t - 128] = W2[t - 128];
    if (t >= 384 && t < 400) b1s[t - 384] = b1[t - 384];
    // init acc with self-loop contribution h1p[n]
    for (int idx = t; idx < 2048; idx += 512) {
        int n = nb0 + (idx >> 4);
        acc[idx] = (n < N_NODES) ? h1p[(size_t)n * 16 + (idx & 15)] : 0.f;
    }
    __syncthreads();
    int cnt = btot[b];
    int start = bbase[b];
    int c = t & 15;
    for (int i = (t >> 4); i < cnt; i += 32) {
        unsigned int e = ebuf[start + i];
        float v = h1p[(size_t)(e >> 7) * 16 + c];
        unsafeAtomicAdd(&acc[(e & 127u) * 16 + c], v);
    }
    __syncthreads();
    // epilogue: per (node,c) compute row @ W2 with on-the-fly relu(u_j)
    for (int idx = t; idx < 2048; idx += 512) {
        int node = idx >> 4;
        int cc = idx & 15;
        int gn = nb0 + node;
        if (gn >= N_NODES) continue;
        float di = dinvb[node];
        float out = 0.f;
#pragma unroll
        for (int j = 0; j < 16; j++) {
            float u = fmaf(di, acc[node * 16 + j], b1s[j]);
            u = u > 0.f ? u : 0.f;
            out = fmaf(u, w2s[j * 16 + cc], out);
        }
        h3p[(size_t)gn * 16 + cc] = out * di;
    }
}

// ---------------- Agg layer 2: LDS accumulate + bias + log_softmax ----------
__global__ __launch_bounds__(512) void kagg2(const float* __restrict__ h3p,
                                             const float* __restrict__ dinv,
                                             const unsigned int* __restrict__ ebuf,
                                             const int* __restrict__ btot,
                                             const int* __restrict__ bbase,
                                             const float* __restrict__ b2,
                                             float* __restrict__ out) {
    __shared__ float acc[128 * 16];
    __shared__ float dinvb[128];
    __shared__ float b2s[16];
    int t = threadIdx.x;
    int b = blockIdx.x;
    int nb0 = b * 128;
    if (t < 128) {
        int n = nb0 + t;
        dinvb[t] = (n < N_NODES) ? dinv[n] : 0.f;
    }
    if (t >= 128 && t < 144) b2s[t - 128] = b2[t - 128];
    for (int idx = t; idx < 2048; idx += 512) {
        int n = nb0 + (idx >> 4);
        acc[idx] = (n < N_NODES) ? h3p[(size_t)n * 16 + (idx & 15)] : 0.f;
    }
    __syncthreads();
    int cnt = btot[b];
    int start = bbase[b];
    int c = t & 15;
    for (int i = (t >> 4); i < cnt; i += 32) {
        unsigned int e = ebuf[start + i];
        float v = h3p[(size_t)(e >> 7) * 16 + c];
        unsafeAtomicAdd(&acc[(e & 127u) * 16 + c], v);
    }
    __syncthreads();
    // epilogue: logits + 16-wide log_softmax (16-lane shuffle groups)
    int grp = t >> 4;   // 0..31
#pragma unroll
    for (int rep = 0; rep < 4; rep++) {
        int node = grp + rep * 32;
        int gn = nb0 + node;
        float di = dinvb[node];
        float logit = fmaf(di, acc[node * 16 + c], b2s[c]);
        float m = logit;
#pragma unroll
        for (int mask = 1; mask < 16; mask <<= 1)
            m = fmaxf(m, __shfl_xor(m, mask, 16));
        float e = expf(logit - m);
        float ssum = e;
#pragma unroll
        for (int mask = 1; mask < 16; mask <<= 1)
            ssum += __shfl_xor(ssum, mask, 16);
        if (gn < N_NODES)
            out[(size_t)gn * 16 + c] = (logit - m) - logf(ssum);
    }
}

extern "C" void kernel_launch(void* const* d_in, const int* in_sizes, int n_in,
                              void* d_out, int out_size, void* d_ws, size_t ws_size,
                              hipStream_t stream) {
    const float* x  = (const float*)d_in[0];
    const float* W1 = (const float*)d_in[1];
    const float* b1 = (const float*)d_in[2];
    const float* W2 = (const float*)d_in[3];
    const float* b2 = (const float*)d_in[4];
    const int*   ei = (const int*)d_in[5];
    const int* src = ei;
    const int* dst = ei + N_EDGES;
    float* out = (float*)d_out;

    // workspace layout (4B elements):
    int* hist_mat  = (int*)d_ws;                    // NBLK*NBP = 784000
    int* base_mat  = hist_mat + NBLK * NBP;         // 784000
    int* btot      = base_mat + NBLK * NBP;         // 1024
    int* bbase     = btot + 1024;                   // 1024
    float* dinv    = (float*)(bbase + 1024);        // 100352
    unsigned int* ebuf = (unsigned int*)(dinv + 100352); // 6.4M
    float* h1p     = (float*)(ebuf + N_EDGES);      // 1.6M
    float* h3p     = h1p + 1600000;                 // 1.6M

    khist<<<NBLK, 256, 0, stream>>>(dst, hist_mat);
    kbtot<<<NBKT, 256, 0, stream>>>(hist_mat, btot);
    kbscan<<<1, 1024, 0, stream>>>(btot, bbase);
    kbase<<<NBKT, 256, 0, stream>>>(hist_mat, bbase, base_mat);
    kscatter<<<NBLK, 256, 0, stream>>>(src, dst, base_mat, ebuf);
    kdeg<<<NBKT, 256, 0, stream>>>(ebuf, btot, bbase, dinv);
    gemm1<<<(N_NODES + 255) / 256, 256, 0, stream>>>(x, W1, dinv, h1p);
    kagg1<<<NBKT, 512, 0, stream>>>(h1p, dinv, ebuf, btot, bbase, b1, W2, h3p);
    kagg2<<<NBKT, 512, 0, stream>>>(h3p, dinv, ebuf, btot, bbase, b2, out);
}

// Round 5
// 1879.489 us; speedup vs baseline: 1.6208x; 1.0101x over previous
//
#include <hip/hip_runtime.h>
#include <hip/hip_bf16.h>
#include <hip/hip_fp16.h>
#include <math.h>

#define N_NODES 100000
#define N_EDGES 6400000
#define D_IN 512
#define D_HID 16

#define NBKT 782        // ceil(100000/128) buckets of 128 nodes (by dst>>7)
#define NBP  784        // padded row stride for (block x bucket) matrices
#define NBLK 250        // scatter blocks (fat: big per-(block,bucket) chunks)
#define EPB  25600      // edges per scatter block (100 per thread * 256)

// ---------------- pass A: per-block bucket histogram (no global atomics) ----
__global__ __launch_bounds__(256) void khist(const int* __restrict__ dst,
                                             int* __restrict__ hist_mat) {
    __shared__ int h[NBP];
    int tid = threadIdx.x;
    int blk = blockIdx.x;
    for (int i = tid; i < NBP; i += 256) h[i] = 0;
    __syncthreads();
    int base = blk * EPB;
#pragma unroll 4
    for (int k = 0; k < 100; k++)
        atomicAdd(&h[dst[base + k * 256 + tid] >> 7], 1);
    __syncthreads();
    for (int i = tid; i < NBKT; i += 256) hist_mat[blk * NBP + i] = h[i];
}

// ---------------- bucket totals ----------------
__global__ __launch_bounds__(256) void kbtot(const int* __restrict__ hist_mat,
                                             int* __restrict__ btot) {
    __shared__ int sd[256];
    int b = blockIdx.x;
    int t = threadIdx.x;
    int s = (t < NBLK) ? hist_mat[t * NBP + b] : 0;
    sd[t] = s;
    __syncthreads();
    for (int off = 128; off > 0; off >>= 1) {
        if (t < off) sd[t] += sd[t + off];
        __syncthreads();
    }
    if (t == 0) btot[b] = sd[0];
}

// ---------------- exclusive scan of bucket totals ----------------
__global__ __launch_bounds__(1024) void kbscan(const int* __restrict__ btot,
                                               int* __restrict__ bbase) {
    __shared__ int sd[1024];
    int t = threadIdx.x;
    int v = (t < NBKT) ? btot[t] : 0;
    sd[t] = v;
    __syncthreads();
    for (int off = 1; off < 1024; off <<= 1) {
        int u = (t >= off) ? sd[t - off] : 0;
        __syncthreads();
        sd[t] += u;
        __syncthreads();
    }
    if (t < NBKT) bbase[t] = sd[t] - v;
}

// ---------------- per-bucket exclusive scan over blocks ----------------
__global__ __launch_bounds__(256) void kbase(const int* __restrict__ hist_mat,
                                             const int* __restrict__ bbase,
                                             int* __restrict__ base_mat) {
    __shared__ int sd[256];
    int b = blockIdx.x;
    int t = threadIdx.x;
    int v = (t < NBLK) ? hist_mat[t * NBP + b] : 0;
    sd[t] = v;
    __syncthreads();
    for (int off = 1; off < 256; off <<= 1) {
        int u = (t >= off) ? sd[t - off] : 0;
        __syncthreads();
        sd[t] += u;
        __syncthreads();
    }
    if (t < NBLK) base_mat[t * NBP + b] = bbase[b] + sd[t] - v;
}

// ---------------- pass C: deterministic scatter via LDS cursors ----------
__global__ __launch_bounds__(256) void kscatter(const int* __restrict__ src,
                                                const int* __restrict__ dst,
                                                const int* __restrict__ base_mat,
                                                unsigned int* __restrict__ ebuf) {
    __shared__ int cur[NBP];
    int tid = threadIdx.x;
    int blk = blockIdx.x;
    for (int i = tid; i < NBKT; i += 256) cur[i] = base_mat[blk * NBP + i];
    __syncthreads();
    int base = blk * EPB;
#pragma unroll 4
    for (int k = 0; k < 100; k++) {
        int e = base + k * 256 + tid;
        int d = dst[e];
        int s = src[e];
        int p = atomicAdd(&cur[d >> 7], 1);
        ebuf[p] = ((unsigned int)s << 7) | (unsigned int)(d & 127);
    }
}

// ---------------- per-bucket degree -> dinv (no global atomics) ----------
__global__ __launch_bounds__(256) void kdeg(const unsigned int* __restrict__ ebuf,
                                            const int* __restrict__ btot,
                                            const int* __restrict__ bbase,
                                            float* __restrict__ dinv) {
    __shared__ int h[128];
    int t = threadIdx.x;
    int b = blockIdx.x;
    if (t < 128) h[t] = 0;
    __syncthreads();
    int cnt = btot[b];
    int start = bbase[b];
    for (int i = t; i < cnt; i += 256)
        atomicAdd(&h[ebuf[start + i] & 127u], 1);
    __syncthreads();
    if (t < 128) {
        int node = b * 128 + t;
        if (node < N_NODES) dinv[node] = rsqrtf((float)h[t] + 1.0f);
    }
}

// ---------------- GEMM1: h1p16 = fp16((x @ W1) * dinv[row]) ----------------
__global__ __launch_bounds__(256) void gemm1(const float* __restrict__ x,
                                             const float* __restrict__ W1,
                                             const float* __restrict__ dinv,
                                             __half* __restrict__ h1p16) {
    __shared__ float xs[256 * 33];
    int tid = threadIdx.x;
    int row0 = blockIdx.x * 256;
    int row = row0 + tid;
    float acc[16];
#pragma unroll
    for (int c = 0; c < 16; c++) acc[c] = 0.f;

    for (int k0 = 0; k0 < D_IN; k0 += 32) {
        __syncthreads();
#pragma unroll
        for (int l = 0; l < 8; l++) {
            int idx = tid + l * 256;
            int r = idx >> 3;
            int f4 = idx & 7;
            int gr = row0 + r;
            float4 v = make_float4(0.f, 0.f, 0.f, 0.f);
            if (gr < N_NODES)
                v = *(const float4*)(x + (size_t)gr * D_IN + k0 + f4 * 4);
            int a = r * 33 + f4 * 4;
            xs[a] = v.x; xs[a + 1] = v.y; xs[a + 2] = v.z; xs[a + 3] = v.w;
        }
        __syncthreads();
#pragma unroll
        for (int kk = 0; kk < 32; kk++) {
            float xv = xs[tid * 33 + kk];
            const float* wr = W1 + (k0 + kk) * 16;
#pragma unroll
            for (int c = 0; c < 16; c++) acc[c] = fmaf(xv, wr[c], acc[c]);
        }
    }
    if (row < N_NODES) {
        float di = dinv[row];
        alignas(16) __half hv[16];
#pragma unroll
        for (int c = 0; c < 16; c++) hv[c] = __float2half(acc[c] * di);
        uint4* o = (uint4*)(h1p16 + (size_t)row * 16);
        o[0] = *(uint4*)hv;
        o[1] = *(uint4*)(hv + 8);
    }
}

// ---------------- Agg layer 1: gather fp16 (L2-resident) + LDS fp32 acc ----
// h3p16[n] = fp16( (relu(dinv[n]*(sum+self)+b1) @ W2) * dinv[n] )
__global__ __launch_bounds__(256) void kagg1(const __half* __restrict__ h1p16,
                                             const float* __restrict__ dinv,
                                             const unsigned int* __restrict__ ebuf,
                                             const int* __restrict__ btot,
                                             const int* __restrict__ bbase,
                                             const float* __restrict__ b1,
                                             const float* __restrict__ W2,
                                             __half* __restrict__ h3p16) {
    __shared__ float acc[128 * 16];
    __shared__ float dinvb[128];
    __shared__ float w2s[256];
    __shared__ float b1s[16];
    int t = threadIdx.x;
    int b = blockIdx.x;
    int nb0 = b * 128;
    if (t < 128) {
        int n = nb0 + t;
        dinvb[t] = (n < N_NODES) ? dinv[n] : 0.f;
    }
    w2s[t] = W2[t];          // 256 threads cover all 256 elements
    if (t < 16) b1s[t] = b1[t];
    // init acc with self-loop contribution
    for (int idx = t; idx < 2048; idx += 256) {
        int n = nb0 + (idx >> 4);
        acc[idx] = (n < N_NODES) ? __half2float(h1p16[(size_t)n * 16 + (idx & 15)]) : 0.f;
    }
    __syncthreads();
    int cnt = btot[b];
    int start = bbase[b];
    int g = t >> 4;       // group 0..15 (16 lanes each)
    int c = t & 15;
    int i = g;
    for (; i + 48 < cnt; i += 64) {
        unsigned int e0 = ebuf[start + i];
        unsigned int e1 = ebuf[start + i + 16];
        unsigned int e2 = ebuf[start + i + 32];
        unsigned int e3 = ebuf[start + i + 48];
        float v0 = __half2float(h1p16[(size_t)(e0 >> 7) * 16 + c]);
        float v1 = __half2float(h1p16[(size_t)(e1 >> 7) * 16 + c]);
        float v2 = __half2float(h1p16[(size_t)(e2 >> 7) * 16 + c]);
        float v3 = __half2float(h1p16[(size_t)(e3 >> 7) * 16 + c]);
        atomicAdd(&acc[(e0 & 127u) * 16 + c], v0);
        atomicAdd(&acc[(e1 & 127u) * 16 + c], v1);
        atomicAdd(&acc[(e2 & 127u) * 16 + c], v2);
        atomicAdd(&acc[(e3 & 127u) * 16 + c], v3);
    }
    for (; i < cnt; i += 16) {
        unsigned int e = ebuf[start + i];
        float v = __half2float(h1p16[(size_t)(e >> 7) * 16 + c]);
        atomicAdd(&acc[(e & 127u) * 16 + c], v);
    }
    __syncthreads();
    // epilogue: per node, u = relu(di*acc+b1); out = (u @ W2) * di
#pragma unroll
    for (int r = 0; r < 8; r++) {
        int node = r * 16 + g;
        int gn = nb0 + node;
        if (gn >= N_NODES) continue;
        float di = dinvb[node];
        float out = 0.f;
#pragma unroll
        for (int j = 0; j < 16; j++) {
            float u = fmaf(di, acc[node * 16 + j], b1s[j]);
            u = u > 0.f ? u : 0.f;
            out = fmaf(u, w2s[j * 16 + c], out);
        }
        h3p16[(size_t)gn * 16 + c] = __float2half(out * di);
    }
}

// ---------------- Agg layer 2: gather fp16 + LDS fp32 acc + log_softmax ----
__global__ __launch_bounds__(256) void kagg2(const __half* __restrict__ h3p16,
                                             const float* __restrict__ dinv,
                                             const unsigned int* __restrict__ ebuf,
                                             const int* __restrict__ btot,
                                             const int* __restrict__ bbase,
                                             const float* __restrict__ b2,
                                             float* __restrict__ out) {
    __shared__ float acc[128 * 16];
    __shared__ float dinvb[128];
    __shared__ float b2s[16];
    int t = threadIdx.x;
    int b = blockIdx.x;
    int nb0 = b * 128;
    if (t < 128) {
        int n = nb0 + t;
        dinvb[t] = (n < N_NODES) ? dinv[n] : 0.f;
    }
    if (t < 16) b2s[t] = b2[t];
    for (int idx = t; idx < 2048; idx += 256) {
        int n = nb0 + (idx >> 4);
        acc[idx] = (n < N_NODES) ? __half2float(h3p16[(size_t)n * 16 + (idx & 15)]) : 0.f;
    }
    __syncthreads();
    int cnt = btot[b];
    int start = bbase[b];
    int g = t >> 4;
    int c = t & 15;
    int i = g;
    for (; i + 48 < cnt; i += 64) {
        unsigned int e0 = ebuf[start + i];
        unsigned int e1 = ebuf[start + i + 16];
        unsigned int e2 = ebuf[start + i + 32];
        unsigned int e3 = ebuf[start + i + 48];
        float v0 = __half2float(h3p16[(size_t)(e0 >> 7) * 16 + c]);
        float v1 = __half2float(h3p16[(size_t)(e1 >> 7) * 16 + c]);
        float v2 = __half2float(h3p16[(size_t)(e2 >> 7) * 16 + c]);
        float v3 = __half2float(h3p16[(size_t)(e3 >> 7) * 16 + c]);
        atomicAdd(&acc[(e0 & 127u) * 16 + c], v0);
        atomicAdd(&acc[(e1 & 127u) * 16 + c], v1);
        atomicAdd(&acc[(e2 & 127u) * 16 + c], v2);
        atomicAdd(&acc[(e3 & 127u) * 16 + c], v3);
    }
    for (; i < cnt; i += 16) {
        unsigned int e = ebuf[start + i];
        float v = __half2float(h3p16[(size_t)(e >> 7) * 16 + c]);
        atomicAdd(&acc[(e & 127u) * 16 + c], v);
    }
    __syncthreads();
    // epilogue: logits + 16-wide log_softmax (16-lane shuffle groups)
#pragma unroll
    for (int r = 0; r < 8; r++) {
        int node = r * 16 + g;
        int gn = nb0 + node;
        float di = dinvb[node];
        float logit = fmaf(di, acc[node * 16 + c], b2s[c]);
        float m = logit;
#pragma unroll
        for (int mask = 1; mask < 16; mask <<= 1)
            m = fmaxf(m, __shfl_xor(m, mask, 16));
        float e = expf(logit - m);
        float ssum = e;
#pragma unroll
        for (int mask = 1; mask < 16; mask <<= 1)
            ssum += __shfl_xor(ssum, mask, 16);
        if (gn < N_NODES)
            out[(size_t)gn * 16 + c] = (logit - m) - logf(ssum);
    }
}

extern "C" void kernel_launch(void* const* d_in, const int* in_sizes, int n_in,
                              void* d_out, int out_size, void* d_ws, size_t ws_size,
                              hipStream_t stream) {
    const float* x  = (const float*)d_in[0];
    const float* W1 = (const float*)d_in[1];
    const float* b1 = (const float*)d_in[2];
    const float* W2 = (const float*)d_in[3];
    const float* b2 = (const float*)d_in[4];
    const int*   ei = (const int*)d_in[5];
    const int* src = ei;
    const int* dst = ei + N_EDGES;
    float* out = (float*)d_out;

    // workspace layout (4B elements unless noted):
    int* hist_mat  = (int*)d_ws;                    // NBLK*NBP = 196000
    int* base_mat  = hist_mat + NBLK * NBP;         // 196000
    int* btot      = base_mat + NBLK * NBP;         // 1024
    int* bbase     = btot + 1024;                   // 1024
    float* dinv    = (float*)(bbase + 1024);        // 100352
    unsigned int* ebuf = (unsigned int*)(dinv + 100352); // 6.4M
    __half* h1p16  = (__half*)(ebuf + N_EDGES);     // 1.6M halves = 3.2MB
    __half* h3p16  = h1p16 + 1605632;               // 3.2MB

    khist<<<NBLK, 256, 0, stream>>>(dst, hist_mat);
    kbtot<<<NBKT, 256, 0, stream>>>(hist_mat, btot);
    kbscan<<<1, 1024, 0, stream>>>(btot, bbase);
    kbase<<<NBKT, 256, 0, stream>>>(hist_mat, bbase, base_mat);
    kscatter<<<NBLK, 256, 0, stream>>>(src, dst, base_mat, ebuf);
    kdeg<<<NBKT, 256, 0, stream>>>(ebuf, btot, bbase, dinv);
    gemm1<<<(N_NODES + 255) / 256, 256, 0, stream>>>(x, W1, dinv, h1p16);
    kagg1<<<NBKT, 256, 0, stream>>>(h1p16, dinv, ebuf, btot, bbase, b1, W2, h3p16);
    kagg2<<<NBKT, 256, 0, stream>>>(h3p16, dinv, ebuf, btot, bbase, b2, out);
}